// Round 7
// baseline (86.829 us; speedup 1.0000x reference)
//
#include <hip/hip_runtime.h>
#include <stdint.h>

// RelationTransform: out[i] = W[relation[i]] @ node_emb[i]
// N=32768, EMB=512, 16 relations, fp32 in/out.
// Prepass: histogram sort (ptok) + W->bf16 only (~25MB).
// GEMM gg7: A staged as fp32 DIRECTLY from X via per-lane-source
// global_load_lds (gather through ptok), bf16 convert at fragment read;
// B staged from pre-converted Ws. Ring-3 LDS (72KB), counted vmcnt(12)
// (never drained in-loop), both-sides XOR swizzle on A and B.

#define EMB 512
#define N_RELC 16
#define BM 128
#define BN 128
#define BK 32
#define NKT 16

typedef __attribute__((ext_vector_type(4))) float f32x4;
typedef __attribute__((ext_vector_type(8))) short bf16x8;

__device__ __forceinline__ unsigned short f2bf(float f) {
  unsigned int u = __float_as_uint(f);
  u += 0x7FFFu + ((u >> 16) & 1u);   // round-to-nearest-even
  return (unsigned short)(u >> 16);
}

__device__ __forceinline__ bf16x8 cvt8(f32x4 lo, f32x4 hi) {
  bf16x8 o;
  o[0] = (short)f2bf(lo[0]); o[1] = (short)f2bf(lo[1]);
  o[2] = (short)f2bf(lo[2]); o[3] = (short)f2bf(lo[3]);
  o[4] = (short)f2bf(hi[0]); o[5] = (short)f2bf(hi[1]);
  o[6] = (short)f2bf(hi[2]); o[7] = (short)f2bf(hi[3]);
  return o;
}

__device__ __forceinline__ void gload_lds16(const void* g, void* l) {
  __builtin_amdgcn_global_load_lds(
      (const __attribute__((address_space(1))) unsigned int*)(uintptr_t)g,
      (__attribute__((address_space(3))) unsigned int*)(uintptr_t)l, 16, 0, 0);
}

__global__ void init_counts(int* cnt) {
  if (threadIdx.x < 32) cnt[threadIdx.x] = 0;
}

// Per-block LDS histogram rank; also fills ptok[0..padn) with -1.
__global__ __launch_bounds__(256) void histo_rank_fill(
    const int* __restrict__ rel, int* cnt, int* pos, int* ptok,
    int n, int padn) {
  __shared__ int lcnt[N_RELC];
  __shared__ int lbase[N_RELC];
  const int tid = threadIdx.x;
  if (tid < N_RELC) lcnt[tid] = 0;
  __syncthreads();
  const int i = blockIdx.x * blockDim.x + tid;
  if (i < padn) ptok[i] = -1;
  int r = 0, myrank = 0;
  if (i < n) { r = rel[i]; myrank = atomicAdd(&lcnt[r], 1); }
  __syncthreads();
  if (tid < N_RELC) lbase[tid] = atomicAdd(&cnt[tid], lcnt[tid]);
  __syncthreads();
  if (i < n) pos[i] = lbase[r] + myrank;
}

// Padded segment bases + tile table (1 block, 64 threads).
__global__ void prefix_tiles64(const int* __restrict__ cnt, int* pbase,
                               int* tinfo, int maxt) {
  __shared__ int sb[N_RELC + 1];
  __shared__ int st[N_RELC + 1];
  if (threadIdx.x == 0) {
    int acc = 0, t = 0;
    for (int r = 0; r < N_RELC; ++r) {
      sb[r] = acc; st[r] = t;
      const int nt = (cnt[r] + BM - 1) / BM;
      acc += nt * BM;
      t += nt;
    }
    sb[N_RELC] = acc; st[N_RELC] = t;
  }
  __syncthreads();
  for (int i = threadIdx.x; i <= N_RELC; i += blockDim.x) pbase[i] = sb[i];
  for (int x = threadIdx.x; x < maxt; x += blockDim.x) {
    int v = -1;
    #pragma unroll
    for (int r = 0; r < N_RELC; ++r)
      if (x >= st[r] && x < st[r + 1]) v = (r << 16) | (x - st[r]);
    tinfo[x] = v;
  }
}

__global__ __launch_bounds__(256) void scatter_ptok(
    const int* __restrict__ rel, const int* __restrict__ pos,
    const int* __restrict__ pbase, int* __restrict__ ptok, int n) {
  const int i = blockIdx.x * blockDim.x + threadIdx.x;
  if (i < n) ptok[pbase[rel[i]] + pos[i]] = i;
}

__global__ __launch_bounds__(256) void convert_W(const float* __restrict__ W,
                                                 unsigned short* __restrict__ Ws,
                                                 int welems) {
  const size_t i = ((size_t)blockIdx.x * 256 + threadIdx.x) * 8;
  if (i >= (size_t)welems) return;
  f32x4 a = *reinterpret_cast<const f32x4*>(W + i);
  f32x4 c = *reinterpret_cast<const f32x4*>(W + i + 4);
  bf16x8 o;
  o[0] = f2bf(a[0]); o[1] = f2bf(a[1]); o[2] = f2bf(a[2]); o[3] = f2bf(a[3]);
  o[4] = f2bf(c[0]); o[5] = f2bf(c[1]); o[6] = f2bf(c[2]); o[7] = f2bf(c[3]);
  *reinterpret_cast<bf16x8*>(Ws + i) = o;
}

// ---------------------------------------------------------------------------
// gg7: 256 threads (4 waves, 2x2; 64x64 out/wave), BK=32, ring-3 LDS.
// A: fp32 [128][32], row = 128B = 8 x 16B slots, stored at phys slot
//    log^(row&7); inverse applied on the per-lane GLOBAL source column.
// B: bf16 [128][32], row = 64B = 4 slots, phys slot = log^((row>>1)&3).
// Per iter: STAGE(t+2) (6 gload_lds) -> vmcnt(counted) -> bar ->
//           COMPUTE(t) (ds_read, cvt, 16 MFMA) -> lgkm(0) -> bar.
// ---------------------------------------------------------------------------

#define STAGE(BUF, KT)                                                         \
  {                                                                            \
    const int kb_ = (KT) * BK;                                                 \
    gload_lds16(asrc[0] + kb_, (char*)&As[BUF][0] + tid * 16);                 \
    gload_lds16(asrc[1] + kb_, (char*)&As[BUF][0] + 4096 + tid * 16);          \
    gload_lds16(asrc[2] + kb_, (char*)&As[BUF][0] + 8192 + tid * 16);          \
    gload_lds16(asrc[3] + kb_, (char*)&As[BUF][0] + 12288 + tid * 16);         \
    gload_lds16(bsrc[0] + kb_, (char*)&Bs[BUF][0] + tid * 16);                 \
    gload_lds16(bsrc[1] + kb_, (char*)&Bs[BUF][0] + 4096 + tid * 16);          \
  }

#define COMPUTE(BUF)                                                           \
  {                                                                            \
    bf16x8 af[4], bfr[4];                                                      \
    _Pragma("unroll")                                                          \
    for (int m = 0; m < 4; ++m) {                                              \
      const float* base_ = &As[BUF][(wr * 64 + m * 16 + lrow) * BK];           \
      f32x4 lo = *(const f32x4*)(base_ + (((gl * 2) ^ swa) * 4));              \
      f32x4 hi = *(const f32x4*)(base_ + (((gl * 2 + 1) ^ swa) * 4));          \
      af[m] = cvt8(lo, hi);                                                    \
    }                                                                          \
    _Pragma("unroll")                                                          \
    for (int nn = 0; nn < 4; ++nn) {                                           \
      const unsigned short* base_ = &Bs[BUF][(wc * 64 + nn * 16 + lrow) * BK]; \
      bfr[nn] = *(const bf16x8*)(base_ + ((gl ^ swb) * 8));                    \
    }                                                                          \
    _Pragma("unroll")                                                          \
    for (int m = 0; m < 4; ++m)                                                \
      _Pragma("unroll")                                                        \
      for (int nn = 0; nn < 4; ++nn)                                           \
        acc[m][nn] = __builtin_amdgcn_mfma_f32_16x16x32_bf16(                  \
            af[m], bfr[nn], acc[m][nn], 0, 0, 0);                              \
  }

#define ITER(T, VM)                                                            \
  {                                                                            \
    if ((T) + 2 < NKT) STAGE(((T) + 2) % 3, (T) + 2);                          \
    asm volatile("s_waitcnt vmcnt(" #VM ")" ::: "memory");                     \
    __builtin_amdgcn_s_barrier();                                              \
    __builtin_amdgcn_sched_barrier(0);                                         \
    COMPUTE((T) % 3);                                                          \
    asm volatile("s_waitcnt lgkmcnt(0)" ::: "memory");                         \
    __builtin_amdgcn_s_barrier();                                              \
    __builtin_amdgcn_sched_barrier(0);                                         \
  }

__global__ __launch_bounds__(256, 2) void gg7(
    const float* __restrict__ X, const unsigned short* __restrict__ Ws,
    const int* __restrict__ pbase, const int* __restrict__ tinfo,
    const int* __restrict__ ptok, float* __restrict__ out)
{
  __shared__ float As[3][BM * BK];            // 3 x 16 KB
  __shared__ unsigned short Bs[3][BN * BK];   // 3 x 8 KB   (total 72 KB)

  const int info = tinfo[blockIdx.x];
  if (info < 0) return;
  const int r = info >> 16;
  const int mt = info & 0xFFFF;
  const int ct = blockIdx.y;
  const int prow0 = pbase[r] + mt * BM;

  const int tid = threadIdx.x;
  const int lane = tid & 63;
  const int wid = tid >> 6;
  const int wr = wid >> 1, wc = wid & 1;
  const int lrow = lane & 15;
  const int gl = lane >> 4;
  const int lrow4 = gl * 4;
  const int swa = lrow & 7;          // A read swizzle
  const int swb = (lrow >> 1) & 3;   // B read swizzle

  // A sources: 4 shots x 32 rows; 8 lanes/row, inverse-swizzled column.
  const int aglog = (tid & 7) ^ ((tid >> 3) & 7);
  const float* asrc[4];
  #pragma unroll
  for (int s = 0; s < 4; ++s) {
    const int row = s * 32 + (tid >> 3);
    int t = ptok[prow0 + row];
    if (t < 0) t = 0;                 // pad rows read token 0 (discarded)
    asrc[s] = X + (size_t)t * EMB + aglog * 4;
  }
  // B sources: 2 shots x 64 rows; 4 lanes/row, inverse-swizzled column.
  const int bglog = (tid & 3) ^ ((tid >> 3) & 3);
  const unsigned short* bsrc[2];
  #pragma unroll
  for (int s = 0; s < 2; ++s) {
    const int row = s * 64 + (tid >> 2);
    bsrc[s] = Ws + ((size_t)r * EMB + (size_t)(ct * BN + row)) * EMB + bglog * 8;
  }

  f32x4 acc[4][4];
  const f32x4 vzero = {0.f, 0.f, 0.f, 0.f};
  #pragma unroll
  for (int m = 0; m < 4; ++m)
    #pragma unroll
    for (int nn = 0; nn < 4; ++nn) acc[m][nn] = vzero;

  STAGE(0, 0);
  STAGE(1, 1);

  ITER(0, 12)  ITER(1, 12)  ITER(2, 12)  ITER(3, 12)
  ITER(4, 12)  ITER(5, 12)  ITER(6, 12)  ITER(7, 12)
  ITER(8, 12)  ITER(9, 12)  ITER(10, 12) ITER(11, 12)
  ITER(12, 12) ITER(13, 12) ITER(14, 6)  ITER(15, 0)

  // Epilogue: D mapping col=lane&15, row=(lane>>4)*4+reg
  #pragma unroll
  for (int m = 0; m < 4; ++m) {
    const int base = prow0 + wr * 64 + m * 16 + lrow4;
    #pragma unroll
    for (int rg = 0; rg < 4; ++rg) {
      const int tok = ptok[base + rg];
      if (tok >= 0) {
        float* orow = out + (size_t)tok * EMB + ct * BN + wc * 64;
        #pragma unroll
        for (int nn = 0; nn < 4; ++nn)
          orow[nn * 16 + lrow] = acc[m][nn][rg];
      }
    }
  }
}

// Safety-net naive kernel (only if ws too small).
__global__ void naive_kernel(const float* __restrict__ X, const int* __restrict__ rel,
                             const float* __restrict__ W, float* __restrict__ out, int n) {
  int i = blockIdx.x;
  if (i >= n) return;
  int r = rel[i];
  const float* x = X + (size_t)i * EMB;
  const float* Wr = W + (size_t)r * EMB * EMB;
  for (int j = threadIdx.x; j < EMB; j += blockDim.x) {
    const float* w = Wr + (size_t)j * EMB;
    float s = 0.f;
    for (int k = 0; k < EMB; ++k) s += w[k] * x[k];
    out[(size_t)i * EMB + j] = s;
  }
}

extern "C" void kernel_launch(void* const* d_in, const int* in_sizes, int n_in,
                              void* d_out, int out_size, void* d_ws, size_t ws_size,
                              hipStream_t stream) {
  const float* X  = (const float*)d_in[0];
  const int* rel  = (const int*)d_in[1];
  const float* W  = (const float*)d_in[2];
  float* out      = (float*)d_out;
  const int n = in_sizes[1];
  const int welems = in_sizes[2];                 // n_rel * EMB * EMB
  const int padn = n + N_RELC * BM;
  const int maxt = (n + BM - 1) / BM + N_RELC;
  const int maxtp = ((maxt + 7) / 8) * 8;         // multiple of 8 (XCD co-location)

  const size_t ints = (size_t)64 + n + padn + maxtp;
  const size_t offW = ((ints * sizeof(int) + 255) / 256) * 256;
  const size_t need = offW + (size_t)welems * 2;

  if (ws_size < need) {
    naive_kernel<<<n, 256, 0, stream>>>(X, rel, W, out, n);
    return;
  }

  int* cnt   = (int*)d_ws;       // 16 (+pad)
  int* pbase = cnt + 16;         // 17
  int* pos   = cnt + 64;         // n
  int* ptok  = pos + n;          // padn
  int* tinfo = ptok + padn;      // maxtp
  unsigned short* Ws = (unsigned short*)((char*)d_ws + offW);

  init_counts<<<1, 32, 0, stream>>>(cnt);
  histo_rank_fill<<<(padn + 255) / 256, 256, 0, stream>>>(rel, cnt, pos, ptok, n, padn);
  prefix_tiles64<<<1, 64, 0, stream>>>(cnt, pbase, tinfo, maxtp);
  scatter_ptok<<<(n + 255) / 256, 256, 0, stream>>>(rel, pos, pbase, ptok, n);
  convert_W<<<(welems / 8 + 255) / 256, 256, 0, stream>>>(W, Ws, welems);

  // grid.x = m-tiles (multiple of 8), grid.y = 4 column tiles: the 4 ct
  // blocks of one m-tile share blockIdx.x % 8 -> same XCD L2 (X reuse).
  dim3 grid(maxtp, EMB / BN);
  gg7<<<grid, 256, 0, stream>>>(X, Ws, pbase, tinfo, ptok, out);
}

// Round 8
// 76.307 us; speedup vs baseline: 1.1379x; 1.1379x over previous
//
#include <hip/hip_runtime.h>
#include <stdint.h>

// RelationTransform: out[i] = W[relation[i]] @ node_emb[i]
// N=32768, EMB=512, 16 relations, fp32 in/out.
// Prepass: histogram sort -> ONE fused kernel (gather X->bf16 sorted Xs +
// ptok, zero pads, convert W->bf16 Ws).
// GEMM gg8: gload_lds bf16 both sides (gg6 operands) + ring-3 LDS with
// counted vmcnt(8) (gg7 schedule, proven correct): 2 iters of load cover,
// no in-loop drain. 48KB LDS -> 3 blocks/CU. grid(4, maxtp): ct fastest
// so the 4 column-tiles of an m-tile are dispatch-adjacent (Xs L2/L3 reuse).

#define EMB 512
#define N_RELC 16
#define BM 128
#define BN 128
#define BK 32
#define NKT 16

typedef __attribute__((ext_vector_type(4))) float f32x4;
typedef __attribute__((ext_vector_type(8))) short bf16x8;

__device__ __forceinline__ unsigned short f2bf(float f) {
  unsigned int u = __float_as_uint(f);
  u += 0x7FFFu + ((u >> 16) & 1u);   // round-to-nearest-even
  return (unsigned short)(u >> 16);
}

__device__ __forceinline__ void gload_lds16(const void* g, void* l) {
  __builtin_amdgcn_global_load_lds(
      (const __attribute__((address_space(1))) unsigned int*)(uintptr_t)g,
      (__attribute__((address_space(3))) unsigned int*)(uintptr_t)l, 16, 0, 0);
}

// Per-block LDS histogram rank; also fills ptok[0..padn) with -1.
__global__ __launch_bounds__(256) void histo_rank_fill(
    const int* __restrict__ rel, int* cnt, int* pos, int* ptok,
    int n, int padn) {
  __shared__ int lcnt[N_RELC];
  __shared__ int lbase[N_RELC];
  const int tid = threadIdx.x;
  if (tid < N_RELC) lcnt[tid] = 0;
  __syncthreads();
  const int i = blockIdx.x * blockDim.x + tid;
  if (i < padn) ptok[i] = -1;
  int r = 0, myrank = 0;
  if (i < n) { r = rel[i]; myrank = atomicAdd(&lcnt[r], 1); }
  __syncthreads();
  if (tid < N_RELC) lbase[tid] = atomicAdd(&cnt[tid], lcnt[tid]);
  __syncthreads();
  if (i < n) pos[i] = lbase[r] + myrank;
}

// Padded segment bases + tile table (1 block, 64 threads).
__global__ void prefix_tiles64(const int* __restrict__ cnt, int* pbase,
                               int* tinfo, int maxt) {
  __shared__ int sb[N_RELC + 1];
  __shared__ int st[N_RELC + 1];
  if (threadIdx.x == 0) {
    int acc = 0, t = 0;
    for (int r = 0; r < N_RELC; ++r) {
      sb[r] = acc; st[r] = t;
      const int nt = (cnt[r] + BM - 1) / BM;
      acc += nt * BM;
      t += nt;
    }
    sb[N_RELC] = acc; st[N_RELC] = t;
  }
  __syncthreads();
  for (int i = threadIdx.x; i <= N_RELC; i += blockDim.x) pbase[i] = sb[i];
  for (int x = threadIdx.x; x < maxt; x += blockDim.x) {
    int v = -1;
    #pragma unroll
    for (int r = 0; r < N_RELC; ++r)
      if (x >= st[r] && x < st[r + 1]) v = (r << 16) | (x - st[r]);
    tinfo[x] = v;
  }
}

// Fused prepass: blocks [0,gb) gather X->Xs (+ptok), [gb,gb+16) zero Xs pads,
// [gb+16, ...) convert W->Ws.
__global__ __launch_bounds__(256) void prep_all(
    const float* __restrict__ X, const float* __restrict__ W,
    const int* __restrict__ rel, const int* __restrict__ pos,
    const int* __restrict__ pbase, const int* __restrict__ cnt,
    unsigned short* __restrict__ Xs, unsigned short* __restrict__ Ws,
    int* __restrict__ ptok, int n, int welems, int gb)
{
  const int b = blockIdx.x;
  if (b < gb) {                       // ---- gather+convert 4 token rows ----
    const int row = b * 4 + (threadIdx.x >> 6);
    const int lane = threadIdx.x & 63;
    if (row >= n) return;
    const int dst = pbase[rel[row]] + pos[row];
    if (lane == 0) ptok[dst] = row;
    const float* src = X + (size_t)row * EMB + lane * 8;
    f32x4 a = *reinterpret_cast<const f32x4*>(src);
    f32x4 c = *reinterpret_cast<const f32x4*>(src + 4);
    bf16x8 o;
    o[0] = f2bf(a[0]); o[1] = f2bf(a[1]); o[2] = f2bf(a[2]); o[3] = f2bf(a[3]);
    o[4] = f2bf(c[0]); o[5] = f2bf(c[1]); o[6] = f2bf(c[2]); o[7] = f2bf(c[3]);
    *reinterpret_cast<bf16x8*>(Xs + (size_t)dst * EMB + lane * 8) = o;
  } else if (b < gb + N_RELC) {       // ---- zero pad rows of relation r ----
    const int r = b - gb;
    const int start = pbase[r] + cnt[r];
    const int end = pbase[r + 1];
    const int nvec = (end - start) * (EMB / 8);
    unsigned short* p = Xs + (size_t)start * EMB;
    const bf16x8 z = {0, 0, 0, 0, 0, 0, 0, 0};
    for (int v = threadIdx.x; v < nvec; v += blockDim.x)
      *reinterpret_cast<bf16x8*>(p + (size_t)v * 8) = z;
  } else {                            // ---- convert W -> bf16 ----
    const size_t i = (((size_t)(b - gb - N_RELC)) * 256 + threadIdx.x) * 8;
    if (i >= (size_t)welems) return;
    f32x4 a = *reinterpret_cast<const f32x4*>(W + i);
    f32x4 c = *reinterpret_cast<const f32x4*>(W + i + 4);
    bf16x8 o;
    o[0] = f2bf(a[0]); o[1] = f2bf(a[1]); o[2] = f2bf(a[2]); o[3] = f2bf(a[3]);
    o[4] = f2bf(c[0]); o[5] = f2bf(c[1]); o[6] = f2bf(c[2]); o[7] = f2bf(c[3]);
    *reinterpret_cast<bf16x8*>(Ws + i) = o;
  }
}

// ---------------------------------------------------------------------------
// gg8: 256 threads (4 waves, 2x2; 64x64 out/wave), BK=32, ring-3 bf16 LDS.
// Per iter: STAGE(t+2) [4 gload_lds] -> vmcnt(8) [stage t landed] -> barrier
//           -> COMPUTE(t) [8 ds_read_b128, 16 MFMA] -> lgkm(0) -> barrier.
// Stage t+2 writes buf (t+2)%3 = buf (t-1)%3 whose readers (compute t-1)
// finished before the previous end-barrier. Loads get ~2 iters of cover.
// ---------------------------------------------------------------------------

#define STAGE(BUF, KT)                                                         \
  {                                                                            \
    const int kb_ = (KT) * BK;                                                 \
    gload_lds16(asrc0 + kb_, (char*)&As[BUF][0] + tid * 16);                   \
    gload_lds16(asrc1 + kb_, (char*)&As[BUF][0] + 4096 + tid * 16);            \
    gload_lds16(bsrc0 + kb_, (char*)&Bs[BUF][0] + tid * 16);                   \
    gload_lds16(bsrc1 + kb_, (char*)&Bs[BUF][0] + 4096 + tid * 16);            \
  }

#define COMPUTE(BUF)                                                           \
  {                                                                            \
    bf16x8 af[4], bfr[4];                                                      \
    _Pragma("unroll")                                                          \
    for (int m = 0; m < 4; ++m)                                                \
      af[m] = *reinterpret_cast<const bf16x8*>(                                \
          &As[BUF][(wr * 64 + m * 16 + lrow) * BK + gl * 8]);                  \
    _Pragma("unroll")                                                          \
    for (int nn = 0; nn < 4; ++nn)                                             \
      bfr[nn] = *reinterpret_cast<const bf16x8*>(                              \
          &Bs[BUF][(wc * 64 + nn * 16 + lrow) * BK + gl * 8]);                 \
    _Pragma("unroll")                                                          \
    for (int m = 0; m < 4; ++m)                                                \
      _Pragma("unroll")                                                        \
      for (int nn = 0; nn < 4; ++nn)                                           \
        acc[m][nn] = __builtin_amdgcn_mfma_f32_16x16x32_bf16(                  \
            af[m], bfr[nn], acc[m][nn], 0, 0, 0);                              \
  }

#define ITER(T, VM)                                                            \
  {                                                                            \
    if ((T) + 2 < NKT) STAGE(((T) + 2) % 3, (T) + 2);                          \
    asm volatile("s_waitcnt vmcnt(" #VM ")" ::: "memory");                     \
    __builtin_amdgcn_s_barrier();                                              \
    __builtin_amdgcn_sched_barrier(0);                                         \
    COMPUTE((T) % 3);                                                          \
    asm volatile("s_waitcnt lgkmcnt(0)" ::: "memory");                         \
    __builtin_amdgcn_s_barrier();                                              \
    __builtin_amdgcn_sched_barrier(0);                                         \
  }

__global__ __launch_bounds__(256, 3) void gg8(
    const unsigned short* __restrict__ Xs, const unsigned short* __restrict__ Ws,
    const int* __restrict__ pbase, const int* __restrict__ tinfo,
    const int* __restrict__ ptok, float* __restrict__ out)
{
  __shared__ unsigned short As[3][BM * BK];   // 3 x 8 KB
  __shared__ unsigned short Bs[3][BN * BK];   // 3 x 8 KB   (48 KB total)

  const int info = tinfo[blockIdx.y];
  if (info < 0) return;
  const int r = info >> 16;
  const int mt = info & 0xFFFF;
  const int ct = blockIdx.x;
  const int prow0 = pbase[r] + mt * BM;

  const int tid = threadIdx.x;
  const int lane = tid & 63;
  const int wid = tid >> 6;
  const int wr = wid >> 1, wc = wid & 1;
  const int lrow = lane & 15;
  const int gl = lane >> 4;
  const int lrow4 = gl * 4;

  // staging: row = tid>>2 (64 rows per shot), col granule = (tid&3)*8 bf16.
  const unsigned short* asrc0 =
      Xs + (size_t)(prow0 + (tid >> 2)) * EMB + (tid & 3) * 8;
  const unsigned short* asrc1 = asrc0 + (size_t)64 * EMB;
  const unsigned short* bsrc0 =
      Ws + ((size_t)r * EMB + (size_t)(ct * BN + (tid >> 2))) * EMB + (tid & 3) * 8;
  const unsigned short* bsrc1 = bsrc0 + (size_t)64 * EMB;

  f32x4 acc[4][4];
  const f32x4 vzero = {0.f, 0.f, 0.f, 0.f};
  #pragma unroll
  for (int m = 0; m < 4; ++m)
    #pragma unroll
    for (int nn = 0; nn < 4; ++nn) acc[m][nn] = vzero;

  STAGE(0, 0);
  STAGE(1, 1);

  ITER(0, 8)   ITER(1, 8)   ITER(2, 8)   ITER(3, 8)
  ITER(4, 8)   ITER(5, 8)   ITER(6, 8)   ITER(7, 8)
  ITER(8, 8)   ITER(9, 8)   ITER(10, 8)  ITER(11, 8)
  ITER(12, 8)  ITER(13, 8)  ITER(14, 4)  ITER(15, 0)

  // Epilogue: D mapping col=lane&15, row=(lane>>4)*4+reg
  #pragma unroll
  for (int m = 0; m < 4; ++m) {
    const int base = prow0 + wr * 64 + m * 16 + lrow4;
    #pragma unroll
    for (int rg = 0; rg < 4; ++rg) {
      const int tok = ptok[base + rg];
      if (tok >= 0) {
        float* orow = out + (size_t)tok * EMB + ct * BN + wc * 64;
        #pragma unroll
        for (int nn = 0; nn < 4; ++nn)
          orow[nn * 16 + lrow] = acc[m][nn][rg];
      }
    }
  }
}

// Safety-net naive kernel (only if ws too small).
__global__ void naive_kernel(const float* __restrict__ X, const int* __restrict__ rel,
                             const float* __restrict__ W, float* __restrict__ out, int n) {
  int i = blockIdx.x;
  if (i >= n) return;
  int r = rel[i];
  const float* x = X + (size_t)i * EMB;
  const float* Wr = W + (size_t)r * EMB * EMB;
  for (int j = threadIdx.x; j < EMB; j += blockDim.x) {
    const float* w = Wr + (size_t)j * EMB;
    float s = 0.f;
    for (int k = 0; k < EMB; ++k) s += w[k] * x[k];
    out[(size_t)i * EMB + j] = s;
  }
}

extern "C" void kernel_launch(void* const* d_in, const int* in_sizes, int n_in,
                              void* d_out, int out_size, void* d_ws, size_t ws_size,
                              hipStream_t stream) {
  const float* X  = (const float*)d_in[0];
  const int* rel  = (const int*)d_in[1];
  const float* W  = (const float*)d_in[2];
  float* out      = (float*)d_out;
  const int n = in_sizes[1];
  const int welems = in_sizes[2];                 // n_rel * EMB * EMB
  const int padn = n + N_RELC * BM;
  const int maxt = (n + BM - 1) / BM + N_RELC;
  const int maxtp = ((maxt + 7) / 8) * 8;

  const size_t ints = (size_t)64 + n + padn + maxtp;
  const size_t offW = ((ints * sizeof(int) + 255) / 256) * 256;
  const size_t offX = offW + (((size_t)welems * 2 + 255) / 256) * 256;
  const size_t need = offX + (size_t)padn * EMB * 2;

  if (ws_size < need) {
    naive_kernel<<<n, 256, 0, stream>>>(X, rel, W, out, n);
    return;
  }

  int* cnt   = (int*)d_ws;       // 16 (+pad to 64)
  int* pbase = cnt + 16;         // 17
  int* pos   = cnt + 64;         // n
  int* ptok  = pos + n;          // padn
  int* tinfo = ptok + padn;      // maxtp
  unsigned short* Ws = (unsigned short*)((char*)d_ws + offW);
  unsigned short* Xs = (unsigned short*)((char*)d_ws + offX);

  const int gb = (n + 3) / 4;                       // gather blocks
  const int wb = (welems / 8 + 255) / 256;          // convert-W blocks

  hipMemsetAsync(cnt, 0, 64 * sizeof(int), stream);
  histo_rank_fill<<<(padn + 255) / 256, 256, 0, stream>>>(rel, cnt, pos, ptok, n, padn);
  prefix_tiles64<<<1, 64, 0, stream>>>(cnt, pbase, tinfo, maxtp);
  prep_all<<<gb + N_RELC + wb, 256, 0, stream>>>(X, W, rel, pos, pbase, cnt,
                                                 Xs, Ws, ptok, n, welems, gb);

  // grid.x = the 4 column tiles (fastest) -> the 4 ct blocks of one m-tile
  // are dispatch-adjacent; Xs rows reused while hot in L2/L3.
  dim3 grid(EMB / BN, maxtp);
  gg8<<<grid, 256, 0, stream>>>(Xs, Ws, pbase, tinfo, ptok, out);
}

// Round 9
// 74.323 us; speedup vs baseline: 1.1683x; 1.0267x over previous
//
#include <hip/hip_runtime.h>
#include <stdint.h>

// RelationTransform: out[i] = W[relation[i]] @ node_emb[i]
// N=32768, EMB=512, 16 relations, fp32 in/out.
// Prepass: histogram sort (ptok) + W->bf16 convert only (~81 MB).
// GEMM gg9: A staged fp32 DIRECTLY from X (per-lane ptok gather via
// global_load_lds, XOR-swizzled 16B slots both sides), B from bf16 Ws.
// 128x256 tile, 512 thr (8 waves, 2x4; 64x64/wave), BK=32, dbuf LDS 64KB,
// ONE barrier per K-tile: vmcnt(0)[covered by full tile]+bar+sched_barrier,
// then front-loaded STAGE(t+1), then ds_read+cvt+16 MFMA (compiler lgkm).

#define EMB 512
#define N_RELC 16
#define BM 128
#define BN 256
#define BK 32
#define NKT 16

typedef __attribute__((ext_vector_type(4))) float f32x4;
typedef __attribute__((ext_vector_type(8))) short bf16x8;

__device__ __forceinline__ unsigned short f2bf(float f) {
  unsigned int u = __float_as_uint(f);
  u += 0x7FFFu + ((u >> 16) & 1u);   // round-to-nearest-even
  return (unsigned short)(u >> 16);
}

__device__ __forceinline__ bf16x8 cvt8(f32x4 lo, f32x4 hi) {
  bf16x8 o;
  o[0] = (short)f2bf(lo[0]); o[1] = (short)f2bf(lo[1]);
  o[2] = (short)f2bf(lo[2]); o[3] = (short)f2bf(lo[3]);
  o[4] = (short)f2bf(hi[0]); o[5] = (short)f2bf(hi[1]);
  o[6] = (short)f2bf(hi[2]); o[7] = (short)f2bf(hi[3]);
  return o;
}

__device__ __forceinline__ void gload_lds16(const void* g, void* l) {
  __builtin_amdgcn_global_load_lds(
      (const __attribute__((address_space(1))) unsigned int*)(uintptr_t)g,
      (__attribute__((address_space(3))) unsigned int*)(uintptr_t)l, 16, 0, 0);
}

// Per-block LDS histogram rank; also fills ptok[0..padn) with -1.
__global__ __launch_bounds__(256) void histo_rank_fill(
    const int* __restrict__ rel, int* cnt, int* pos, int* ptok,
    int n, int padn) {
  __shared__ int lcnt[N_RELC];
  __shared__ int lbase[N_RELC];
  const int tid = threadIdx.x;
  if (tid < N_RELC) lcnt[tid] = 0;
  __syncthreads();
  const int i = blockIdx.x * blockDim.x + tid;
  if (i < padn) ptok[i] = -1;
  int r = 0, myrank = 0;
  if (i < n) { r = rel[i]; myrank = atomicAdd(&lcnt[r], 1); }
  __syncthreads();
  if (tid < N_RELC) lbase[tid] = atomicAdd(&cnt[tid], lcnt[tid]);
  __syncthreads();
  if (i < n) pos[i] = lbase[r] + myrank;
}

// Padded segment bases + tile table (1 block, 64 threads).
__global__ void prefix_tiles64(const int* __restrict__ cnt, int* pbase,
                               int* tinfo, int maxt) {
  __shared__ int sb[N_RELC + 1];
  __shared__ int st[N_RELC + 1];
  if (threadIdx.x == 0) {
    int acc = 0, t = 0;
    for (int r = 0; r < N_RELC; ++r) {
      sb[r] = acc; st[r] = t;
      const int nt = (cnt[r] + BM - 1) / BM;
      acc += nt * BM;
      t += nt;
    }
    sb[N_RELC] = acc; st[N_RELC] = t;
  }
  __syncthreads();
  for (int i = threadIdx.x; i <= N_RELC; i += blockDim.x) pbase[i] = sb[i];
  for (int x = threadIdx.x; x < maxt; x += blockDim.x) {
    int v = -1;
    #pragma unroll
    for (int r = 0; r < N_RELC; ++r)
      if (x >= st[r] && x < st[r + 1]) v = (r << 16) | (x - st[r]);
    tinfo[x] = v;
  }
}

__global__ __launch_bounds__(256) void scatter_ptok(
    const int* __restrict__ rel, const int* __restrict__ pos,
    const int* __restrict__ pbase, int* __restrict__ ptok, int n) {
  const int i = blockIdx.x * blockDim.x + threadIdx.x;
  if (i < n) ptok[pbase[rel[i]] + pos[i]] = i;
}

__global__ __launch_bounds__(256) void convert_W(const float* __restrict__ W,
                                                 unsigned short* __restrict__ Ws,
                                                 int welems) {
  const size_t i = ((size_t)blockIdx.x * 256 + threadIdx.x) * 8;
  if (i >= (size_t)welems) return;
  f32x4 a = *reinterpret_cast<const f32x4*>(W + i);
  f32x4 c = *reinterpret_cast<const f32x4*>(W + i + 4);
  bf16x8 o;
  o[0] = f2bf(a[0]); o[1] = f2bf(a[1]); o[2] = f2bf(a[2]); o[3] = f2bf(a[3]);
  o[4] = f2bf(c[0]); o[5] = f2bf(c[1]); o[6] = f2bf(c[2]); o[7] = f2bf(c[3]);
  *reinterpret_cast<bf16x8*>(Ws + i) = o;
}

// ---------------------------------------------------------------------------
// gg9. LDS: As fp32 [2][128][32] (16KB/side, rows 128B = 8 16B-slots, stored
// at phys slot log^(row&7); inverse on per-lane global source column ->
// fragment reads hit all 8 bank-quads uniformly). Bs bf16 [2][256][32]
// (16KB/side, 64B rows are conflict-free for the b128 fragment pattern).
// Per K-tile: vmcnt(0)+barrier+sched_barrier -> STAGE(t+1) [4 gload_lds,
// ~full tile of latency cover] -> 8 A-reads+cvt, 4 B-reads, 16 MFMA.
// ---------------------------------------------------------------------------

#define STAGE(S, KT)                                                           \
  {                                                                            \
    const int kb_ = (KT) * BK;                                                 \
    gload_lds16(asrc0 + kb_, (char*)&As[S][0] + tid * 16);                     \
    gload_lds16(asrc1 + kb_, (char*)&As[S][0] + 8192 + tid * 16);              \
    gload_lds16(bsrc0 + kb_, (char*)&Bs[S][0] + tid * 16);                     \
    gload_lds16(bsrc1 + kb_, (char*)&Bs[S][0] + 8192 + tid * 16);              \
  }

__global__ __launch_bounds__(512, 4) void gg9(
    const float* __restrict__ X, const unsigned short* __restrict__ Ws,
    const int* __restrict__ pbase, const int* __restrict__ tinfo,
    const int* __restrict__ ptok, float* __restrict__ out)
{
  __shared__ float As[2][BM * BK];            // 2 x 16 KB
  __shared__ unsigned short Bs[2][BN * BK];   // 2 x 16 KB  (64 KB total)

  // Chunked XCD swizzle: XCD c owns a contiguous chunk of logical ids, so
  // the 2 ct-siblings of an m-tile AND same-relation runs share one L2.
  const int g8 = gridDim.x >> 3;
  const int lid = (blockIdx.x & 7) * g8 + (blockIdx.x >> 3);
  const int info = tinfo[lid >> 1];
  if (info < 0) return;
  const int r = info >> 16;
  const int mt = info & 0xFFFF;
  const int ct = lid & 1;
  const int prow0 = pbase[r] + mt * BM;

  const int tid = threadIdx.x;
  const int lane = tid & 63;
  const int wid = tid >> 6;
  const int wr = wid >> 2;          // 0..1 : 64-row band
  const int wc = wid & 3;           // 0..3 : 64-col band
  const int lrow = lane & 15;
  const int gl = lane >> 4;

  // A staging (fp32 gather): shot h covers rows h*64 + (tid>>3); phys slot
  // tid&7 must hold logical slot (tid&7)^(row&7) -> source col swizzled.
  const int arow = tid >> 3;
  const int aslot = (tid & 7) ^ (arow & 7);
  int tok0 = ptok[prow0 + arow];       if (tok0 < 0) tok0 = 0;
  int tok1 = ptok[prow0 + 64 + arow];  if (tok1 < 0) tok1 = 0;
  const float* asrc0 = X + (size_t)tok0 * EMB + aslot * 4;
  const float* asrc1 = X + (size_t)tok1 * EMB + aslot * 4;
  // B staging (bf16, linear): shot j covers rows ct*256 + j*128 + (tid>>2).
  const unsigned short* bsrc0 =
      Ws + ((size_t)r * EMB + (size_t)(ct * BN + (tid >> 2))) * EMB + (tid & 3) * 8;
  const unsigned short* bsrc1 = bsrc0 + (size_t)128 * EMB;

  f32x4 acc[4][4];
  const f32x4 vzero = {0.f, 0.f, 0.f, 0.f};
  #pragma unroll
  for (int m = 0; m < 4; ++m)
    #pragma unroll
    for (int nn = 0; nn < 4; ++nn) acc[m][nn] = vzero;

  STAGE(0, 0);

  #pragma unroll
  for (int t = 0; t < NKT; ++t) {
    asm volatile("s_waitcnt vmcnt(0)" ::: "memory");   // tile t landed (covered)
    __builtin_amdgcn_s_barrier();                      // side t^1 readers done
    __builtin_amdgcn_sched_barrier(0);
    if (t + 1 < NKT) STAGE((t + 1) & 1, t + 1);
    const int s = t & 1;

    bf16x8 af[4];
    #pragma unroll
    for (int m = 0; m < 4; ++m) {
      const int rr = wr * 64 + m * 16 + lrow;
      const float* base_ = &As[s][rr * BK];
      f32x4 lo = *reinterpret_cast<const f32x4*>(base_ + (((gl * 2)     ^ (rr & 7)) * 4));
      f32x4 hi = *reinterpret_cast<const f32x4*>(base_ + (((gl * 2 + 1) ^ (rr & 7)) * 4));
      af[m] = cvt8(lo, hi);
    }
    #pragma unroll
    for (int nn = 0; nn < 4; ++nn) {
      bf16x8 bfr = *reinterpret_cast<const bf16x8*>(
          &Bs[s][(wc * 64 + nn * 16 + lrow) * BK + gl * 8]);
      #pragma unroll
      for (int m = 0; m < 4; ++m)
        acc[m][nn] = __builtin_amdgcn_mfma_f32_16x16x32_bf16(
            af[m], bfr, acc[m][nn], 0, 0, 0);
    }
  }

  // Epilogue: D mapping col=lane&15, row=(lane>>4)*4+reg
  #pragma unroll
  for (int m = 0; m < 4; ++m) {
    const int base = prow0 + wr * 64 + m * 16 + gl * 4;
    #pragma unroll
    for (int rg = 0; rg < 4; ++rg) {
      const int tok = ptok[base + rg];
      if (tok >= 0) {
        float* orow = out + (size_t)tok * EMB + ct * BN + wc * 64;
        #pragma unroll
        for (int nn = 0; nn < 4; ++nn)
          orow[nn * 16 + lrow] = acc[m][nn][rg];
      }
    }
  }
}

// Safety-net naive kernel (only if ws too small).
__global__ void naive_kernel(const float* __restrict__ X, const int* __restrict__ rel,
                             const float* __restrict__ W, float* __restrict__ out, int n) {
  int i = blockIdx.x;
  if (i >= n) return;
  int r = rel[i];
  const float* x = X + (size_t)i * EMB;
  const float* Wr = W + (size_t)r * EMB * EMB;
  for (int j = threadIdx.x; j < EMB; j += blockDim.x) {
    const float* w = Wr + (size_t)j * EMB;
    float s = 0.f;
    for (int k = 0; k < EMB; ++k) s += w[k] * x[k];
    out[(size_t)i * EMB + j] = s;
  }
}

extern "C" void kernel_launch(void* const* d_in, const int* in_sizes, int n_in,
                              void* d_out, int out_size, void* d_ws, size_t ws_size,
                              hipStream_t stream) {
  const float* X  = (const float*)d_in[0];
  const int* rel  = (const int*)d_in[1];
  const float* W  = (const float*)d_in[2];
  float* out      = (float*)d_out;
  const int n = in_sizes[1];
  const int welems = in_sizes[2];                 // n_rel * EMB * EMB
  const int padn = n + N_RELC * BM;
  const int maxt = (n + BM - 1) / BM + N_RELC;
  const int maxtp = ((maxt + 7) / 8) * 8;         // %8 == 0

  const size_t ints = (size_t)64 + n + padn + maxtp;
  const size_t offW = ((ints * sizeof(int) + 255) / 256) * 256;
  const size_t need = offW + (size_t)welems * 2;

  if (ws_size < need) {
    naive_kernel<<<n, 256, 0, stream>>>(X, rel, W, out, n);
    return;
  }

  int* cnt   = (int*)d_ws;       // 16 (+pad to 64)
  int* pbase = cnt + 16;         // 17
  int* pos   = cnt + 64;         // n
  int* ptok  = pos + n;          // padn
  int* tinfo = ptok + padn;      // maxtp
  unsigned short* Ws = (unsigned short*)((char*)d_ws + offW);

  hipMemsetAsync(cnt, 0, 64 * sizeof(int), stream);
  histo_rank_fill<<<(padn + 255) / 256, 256, 0, stream>>>(rel, cnt, pos, ptok, n, padn);
  prefix_tiles64<<<1, 64, 0, stream>>>(cnt, pbase, tinfo, maxtp);
  scatter_ptok<<<(n + 255) / 256, 256, 0, stream>>>(rel, pos, pbase, ptok, n);
  convert_W<<<(welems / 8 + 255) / 256, 256, 0, stream>>>(W, Ws, welems);

  // 2 blocks (ct=0/1) per m-tile; grid = 2*maxtp (multiple of 16).
  gg9<<<2 * maxtp, 512, 0, stream>>>(X, Ws, pbase, tinfo, ptok, out);
}